// Round 2
// baseline (346.787 us; speedup 1.0000x reference)
//
#include <hip/hip_runtime.h>

#define NFR 500   // n_frames
#define NFQ 320   // n_freq
#define NB  2     // batch
#define NC  6     // n_chan
#define NS  4     // n_src
#define NBK 2     // n_chan - n_src
#define NT  4     // n_taps
#define NDLY 1    // n_delay
#define EPSF 1e-3f
#define TINYF 1e-20f

__device__ __forceinline__ float2 mkc(float r, float i){ return make_float2(r,i); }
__device__ __forceinline__ float2 cadd(float2 a, float2 b){ return mkc(a.x+b.x, a.y+b.y); }
__device__ __forceinline__ float2 csub(float2 a, float2 b){ return mkc(a.x-b.x, a.y-b.y); }
__device__ __forceinline__ float2 cmul(float2 a, float2 b){ return mkc(a.x*b.x - a.y*b.y, a.x*b.y + a.y*b.x); }
__device__ __forceinline__ float2 cmulc(float2 a, float2 b){ // a * conj(b)
  return mkc(a.x*b.x + a.y*b.y, a.y*b.x - a.x*b.y);
}
__device__ __forceinline__ float2 conjc(float2 a){ return mkc(a.x, -a.y); }
__device__ __forceinline__ float  cmag2(float2 a){ return a.x*a.x + a.y*a.y; }
__device__ __forceinline__ float2 cscale(float2 a, float s){ return mkc(a.x*s, a.y*s); }
__device__ __forceinline__ float2 cinv(float2 a){ float m = a.x*a.x + a.y*a.y; return mkc(a.x/m, -a.y/m); }

__device__ __forceinline__ float wred64(float v){
#pragma unroll
  for (int o = 32; o > 0; o >>= 1) v += __shfl_xor(v, o, 64);
  return v;
}

// ---------------------------------------------------------------------------
// init: C_XX -> J (4x4 diag-loaded solve), W/A = eye, Y = X[:4], Z = J X - X[4:]
// ---------------------------------------------------------------------------
__global__ __launch_bounds__(256) void k_init(
  const float* __restrict__ Xr, const float* __restrict__ Xi,
  float2* __restrict__ Yg, float2* __restrict__ Zg,
  float2* __restrict__ Wg, float2* __restrict__ Jg, float2* __restrict__ Ag)
{
  __shared__ float2 sX[NC][NFR];
  __shared__ float2 sC[NS][NC];
  __shared__ float2 sJl[NBK][NS];

  const int bf = blockIdx.x;
  const int b = bf / NFQ, f = bf % NFQ;
  const int tid = threadIdx.x, wv = tid >> 6, lane = tid & 63;

  for (int c = 0; c < NC; ++c) {
    const size_t base = ((size_t)(b*NC + c)*NFQ + f)*NFR;
    for (int n = tid; n < NFR; n += 256)
      sX[c][n] = mkc(Xr[base+n], Xi[base+n]);
  }
  __syncthreads();

  // C_XX[s][d] = (1/N) sum_n X_s conj(X_d), s<4, d<6
  for (int p = wv; p < NS*NC; p += 4) {
    int s = p / NC, d = p % NC;
    float ar = 0.f, ai = 0.f;
    for (int n = lane; n < NFR; n += 64) {
      float2 xs = sX[s][n], xd = sX[d][n];
      ar += xs.x*xd.x + xs.y*xd.y;
      ai += xs.y*xd.x - xs.x*xd.y;
    }
    ar = wred64(ar); ai = wred64(ai);
    if (lane == 0) sC[s][d] = mkc(ar*(1.f/NFR), ai*(1.f/NFR));
  }
  __syncthreads();

  if (tid == 0) {
    float2 M[NS][NC];
    for (int s = 0; s < NS; ++s)
      for (int d = 0; d < NC; ++d) M[s][d] = sC[s][d];
    float dsum = 0.f;
    for (int s = 0; s < NS; ++s) dsum += sqrtf(cmag2(M[s][s]));
    float load = fmaxf(dsum*1e-5f, 1e-5f);
    for (int s = 0; s < NS; ++s) M[s][s].x += load;
    // Gauss-Jordan w/ partial pivoting on [4x4 | 4x2]
    for (int col = 0; col < NS; ++col) {
      int piv = col; float best = cmag2(M[col][col]);
      for (int r = col+1; r < NS; ++r) { float m = cmag2(M[r][col]); if (m > best){best=m; piv=r;} }
      if (piv != col) for (int k = 0; k < NC; ++k) { float2 t=M[col][k]; M[col][k]=M[piv][k]; M[piv][k]=t; }
      float2 ip = cinv(M[col][col]);
      for (int k = col; k < NC; ++k) M[col][k] = cmul(M[col][k], ip);
      for (int r = 0; r < NS; ++r) if (r != col) {
        float2 fac = M[r][col];
        for (int k = col; k < NC; ++k) M[r][k] = csub(M[r][k], cmul(fac, M[col][k]));
      }
    }
    for (int k = 0; k < NBK; ++k)
      for (int s = 0; s < NS; ++s) sJl[k][s] = conjc(M[s][NS+k]);
  }
  __syncthreads();

  if (tid < NBK*NS) {
    int k = tid / NS, s = tid % NS;
    Jg[((size_t)(b*NBK+k)*NFQ + f)*NS + s] = sJl[k][s];
  } else if (tid < NBK*NS + NS*NC) {
    int t = tid - NBK*NS; int s = t / NC, d = t % NC;
    Wg[((size_t)(b*NS+s)*NFQ + f)*NC + d] = (s==d) ? mkc(1.f,0.f) : mkc(0.f,0.f);
  } else if (tid < NBK*NS + NS*NC + NS*NS) {
    int t = tid - NBK*NS - NS*NC; int s = t / NS, d = t % NS;
    Ag[((size_t)(b*NS+s)*NFQ + f)*NS + d] = (s==d) ? mkc(1.f,0.f) : mkc(0.f,0.f);
  }
  for (int c = 0; c < NS; ++c) {
    const size_t base = ((size_t)(b*NS + c)*NFQ + f)*NFR;
    for (int n = tid; n < NFR; n += 256) Yg[base+n] = sX[c][n];
  }
  for (int k = 0; k < NBK; ++k) {
    const size_t base = ((size_t)(b*NBK + k)*NFQ + f)*NFR;
    for (int n = tid; n < NFR; n += 256) {
      float2 acc = cscale(sX[NS+k][n], -1.f);
      for (int s = 0; s < NS; ++s) acc = cadd(acc, cmul(sJl[k][s], sX[s][n]));
      Zg[base+n] = acc;
    }
  }
}

// ---------------------------------------------------------------------------
// w[b,s,n] = 1 / max(mean_f |Y[b,s,f,n]|^2, EPS)   (Y complex in workspace)
// ---------------------------------------------------------------------------
__global__ __launch_bounds__(512) void k_w(const float2* __restrict__ Yg, float* __restrict__ wg)
{
  const int bs = blockIdx.x;
  const int n = threadIdx.x;
  if (n >= NFR) return;
  const float2* row = Yg + (size_t)bs*NFQ*NFR;
  float acc = 0.f;
  for (int f = 0; f < NFQ; ++f) { float2 y = row[(size_t)f*NFR + n]; acc += y.x*y.x + y.y*y.y; }
  wg[bs*NFR + n] = 1.0f / fmaxf(acc * (1.0f/(float)NFQ), EPSF);
}

// ---------------------------------------------------------------------------
// one full iss_updates iteration per (b,f) block (H is dead -> skipped)
// writes complex Y back to workspace AND re(Y) to d_out (float32 layout)
// ---------------------------------------------------------------------------
__global__ __launch_bounds__(256) void k_iter(
  const float* __restrict__ Xr, const float* __restrict__ Xi,
  float2* __restrict__ Yg, float2* __restrict__ Zg,
  float2* __restrict__ Wg, float2* __restrict__ Jg, float2* __restrict__ Ag,
  const float* __restrict__ wg, float* __restrict__ outR)
{
  __shared__ float2 sX[NC][NFR];
  __shared__ float2 sY[NS][NFR];
  __shared__ float2 sZ[NBK][NFR];
  __shared__ float  sw[NS][NFR];
  __shared__ float2 sS[NFR];
  __shared__ float2 sW[NS][NC];
  __shared__ float2 sJ[NBK][NS];
  __shared__ float2 sA[NS][NS];
  __shared__ float2 sB[NS][2*NS];
  __shared__ float2 sv[NC];
  __shared__ float2 sg[NC];
  __shared__ float2 sgo[NS];
  __shared__ float2 sp[NC];
  __shared__ float  sd[NC];
  __shared__ float2 sv2[NS], sAv[NS], sgA[NS];
  __shared__ float2 sWsrc[NC];
  __shared__ float2 sEll, sMul;

  const int bf = blockIdx.x;
  const int b = bf / NFQ, f = bf % NFQ;
  const int tid = threadIdx.x, wv = tid >> 6, lane = tid & 63;

  // ---- load state into LDS
  for (int c = 0; c < NC; ++c) {
    const size_t base = ((size_t)(b*NC + c)*NFQ + f)*NFR;
    for (int n = tid; n < NFR; n += 256) sX[c][n] = mkc(Xr[base+n], Xi[base+n]);
  }
  for (int c = 0; c < NS; ++c) {
    const size_t yb = ((size_t)(b*NS + c)*NFQ + f)*NFR;
    for (int n = tid; n < NFR; n += 256) { sY[c][n] = Yg[yb+n]; sw[c][n] = wg[(b*NS+c)*NFR + n]; }
  }
  for (int k = 0; k < NBK; ++k) {
    const size_t zb = ((size_t)(b*NBK + k)*NFQ + f)*NFR;
    for (int n = tid; n < NFR; n += 256) sZ[k][n] = Zg[zb+n];
  }
  if (tid < NS*NC) sW[tid/NC][tid%NC] = Wg[((size_t)(b*NS + tid/NC)*NFQ + f)*NC + tid%NC];
  else if (tid < NS*NC + NBK*NS) { int t=tid-NS*NC; sJ[t/NS][t%NS] = Jg[((size_t)(b*NBK+t/NS)*NFQ+f)*NS + t%NS]; }
  else if (tid < NS*NC + NBK*NS + NS*NS) { int t=tid-NS*NC-NBK*NS; sA[t/NS][t%NS] = Ag[((size_t)(b*NS+t/NS)*NFQ+f)*NS + t%NS]; }
  __syncthreads();

  // ================= bak loop: bak_update + mat_up2 =================
  for (int bak = 0; bak < NBK; ++bak) {
    // stage Zs = Z[bak] + X[4+bak]
    for (int n = tid; n < NFR; n += 256)
      sS[n] = cadd(sZ[bak][n], sX[NS+bak][n]);
    __syncthreads();

    // p,d over 6 channels (wave wv -> channels wv, wv+4)
    for (int c = wv; c < NC; c += 4) {
      float pr = 0.f, pi = 0.f, dd = 0.f;
      if (c < NS) {
        for (int n = lane; n < NFR; n += 64) {
          float2 y = sY[c][n]; float2 zs = sS[n]; float wgt = sw[c][n];
          pr += wgt*(y.x*zs.x + y.y*zs.y);
          pi += wgt*(y.y*zs.x - y.x*zs.y);
          dd += wgt*(zs.x*zs.x + zs.y*zs.y);
        }
      } else {
        for (int n = lane; n < NFR; n += 64) {
          float2 y = sZ[c-NS][n]; float2 zs = sS[n];
          pr += (y.x*zs.x + y.y*zs.y);
          pi += (y.y*zs.x - y.x*zs.y);
          dd += (zs.x*zs.x + zs.y*zs.y);
        }
      }
      pr = wred64(pr); pi = wred64(pi); dd = wred64(dd);
      if (lane == 0) { sp[c] = mkc(pr*(1.f/NFR), pi*(1.f/NFR)); sd[c] = dd*(1.f/NFR); }
    }
    __syncthreads();

    // g[c] = conj( sum_s J[bak][s] * A2[s][c] )
    if (tid < NC) {
      int c = tid; float2 acc = mkc(0.f,0.f);
      for (int s = 0; s < NS; ++s) {
        float2 a2;
        if (c < NS) a2 = sA[s][c];
        else {
          a2 = mkc(0.f,0.f);
          for (int k = 0; k < NS; ++k) a2 = cadd(a2, cmul(sA[s][k], sW[k][c]));
        }
        acc = cadd(acc, cmul(sJ[bak][s], a2));
      }
      sg[c] = conjc(acc);
    }
    __syncthreads();

    // bak_update_vector scalars
    if (tid == 0) {
      float gdg = 0.f; float2 gdp = mkc(0.f,0.f);
      for (int c = 0; c < NC; ++c) {
        float id = 1.0f/(sd[c] + EPSF);
        gdg += cmag2(sg[c]) * id;
        float2 t = cmulc(sp[c], sg[c]);   // p * conj(g)
        gdp.x += t.x*id; gdp.y += t.y*id;
      }
      float2 bb = mkc(1.0f - gdp.x, -gdp.y);
      float b1 = cmag2(bb);
      float a = b1*gdg + TINYF;
      float beta = (-b1 + sqrtf(b1*b1 + 4.0f*a)) / (2.0f*a);
      float2 ell;
      if (b1 > EPSF*EPSF) ell = cscale(bb, beta);
      else { float e2 = 1.0f/sqrtf(EPSF + gdg); ell = mkc(e2, 0.f); }
      sEll = ell;
    }
    __syncthreads();

    if (tid < NC) {
      float2 num = csub(sp[tid], cmul(sEll, sg[tid]));
      sv[tid] = cscale(num, 1.0f/(sd[tid] + EPSF));
    } else if (tid >= 8 && tid < 8+NS) {
      sgo[tid-8] = sJ[bak][tid-8];          // g for mat_up2 = old J[bak]
    }
    __syncthreads();

    // YZ -= v (x) Zs ; plus v2 (small)
    for (int c = wv; c < NC; c += 4) {
      float2 vc = sv[c];
      if (c < NS) { for (int n = lane; n < NFR; n += 64) sY[c][n]    = csub(sY[c][n],    cmul(vc, sS[n])); }
      else        { for (int n = lane; n < NFR; n += 64) sZ[c-NS][n] = csub(sZ[c-NS][n], cmul(vc, sS[n])); }
    }
    if (tid < NS) {
      float2 t = sv[tid];
      t = cadd(t, cmul(sW[tid][NS+0], sv[NS+0]));
      t = cadd(t, cmul(sW[tid][NS+1], sv[NS+1]));
      sv2[tid] = t;
    }
    __syncthreads();

    if (tid < NS) {
      float2 acc = mkc(0.f,0.f);
      for (int c = 0; c < NS; ++c) acc = cadd(acc, cmul(sA[tid][c], sv2[c]));
      sAv[tid] = acc;
    } else if (tid < 2*NS) {
      int c = tid - NS; float2 acc = mkc(0.f,0.f);
      for (int s = 0; s < NS; ++s) acc = cadd(acc, cmul(sgo[s], sA[s][c]));
      sgA[c] = acc;
    }
    __syncthreads();

    if (tid == 0) {
      float2 den = mkc(1.f,0.f);
      for (int c = 0; c < NS; ++c) den = csub(den, cmul(sv2[c], sgA[c]));
      float m2 = cmag2(den) + EPSF;
      sMul = mkc(den.x/m2, -den.y/m2);
    }
    __syncthreads();

    if (tid < 16) {                  // W[:, :4] -= v[:4] (x) g
      int c = tid >> 2, d = tid & 3;
      sW[c][d] = csub(sW[c][d], cmul(sv[c], sgo[d]));
    } else if (tid < 24) {           // J -= v[4:] (x) g
      int k = (tid-16) >> 2, d = (tid-16) & 3;
      sJ[k][d] = csub(sJ[k][d], cmul(sv[NS+k], sgo[d]));
    } else if (tid < 40) {           // A += Av (x) (gA * mul)
      int s = (tid-24) >> 2, c = (tid-24) & 3;
      sA[s][c] = cadd(sA[s][c], cmul(sAv[s], cmul(sgA[c], sMul)));
    }
    __syncthreads();
  }

  // ================= type1 loop (src) + mat_up1 =================
  for (int src = 0; src < NS; ++src) {
    for (int n = tid; n < NFR; n += 256) sS[n] = sY[src][n];
    if (tid < NC) sWsrc[tid] = sW[src][tid];
    __syncthreads();

    {
      int c = wv;
      float nr = 0.f, ni = 0.f, dd = 0.f;
      for (int n = lane; n < NFR; n += 64) {
        float2 y = sY[c][n]; float2 s = sS[n]; float wgt = sw[c][n];
        nr += wgt*(y.x*s.x + y.y*s.y);
        ni += wgt*(y.y*s.x - y.x*s.y);
        dd += wgt*(s.x*s.x + s.y*s.y);
      }
      nr = wred64(nr)*(1.f/NFR); ni = wred64(ni)*(1.f/NFR); dd = wred64(dd)*(1.f/NFR);
      float2 vc;
      if (c == src) vc = mkc(1.0f - 1.0f/sqrtf(fmaxf(dd, EPSF)), 0.f);
      else          vc = cscale(mkc(nr, ni), 1.0f/fmaxf(dd, EPSF));
      if (lane == 0) sv[c] = vc;
      for (int n = lane; n < NFR; n += 64) sY[c][n] = csub(sY[c][n], cmul(vc, sS[n]));
      if (lane < NC) sW[c][lane] = csub(sW[c][lane], cmul(vc, sWsrc[lane]));
    }
    __syncthreads();

    if (tid < NS) {   // mat_up1: A[:, src] += (A v) / (1 - v[src] + eps)
      float2 acc = mkc(0.f,0.f);
      for (int c = 0; c < NS; ++c) acc = cadd(acc, cmul(sA[tid][c], sv[c]));
      float den = 1.0f - sv[src].x + EPSF;   // v[src] is real
      acc = cscale(acc, 1.0f/den);
      sA[tid][src] = cadd(sA[tid][src], acc);
    }
    __syncthreads();
  }

  // ================= type2 loop (barrier-free; wave owns Y[c], W row c) =====
  {
    int c = wv;
    for (int bak = 0; bak < NBK; ++bak) {
      float nr = 0.f, ni = 0.f, dd = 0.f;
      for (int n = lane; n < NFR; n += 64) {
        float2 y = sY[c][n]; float2 z = sZ[bak][n]; float wgt = sw[c][n];
        nr += wgt*(y.x*z.x + y.y*z.y);
        ni += wgt*(y.y*z.x - y.x*z.y);
        dd += wgt*(z.x*z.x + z.y*z.y);
      }
      nr = wred64(nr); ni = wred64(ni); dd = wred64(dd);   // no 1/N here
      float2 vc = cscale(mkc(nr,ni), 1.0f/fmaxf(dd, EPSF));
      for (int n = lane; n < NFR; n += 64) sY[c][n] = csub(sY[c][n], cmul(vc, sZ[bak][n]));
      if (lane < NS) sW[c][lane] = csub(sW[c][lane], cmul(vc, sJ[bak][lane]));
      if (lane == NS) sW[c][NS+bak] = cadd(sW[c][NS+bak], vc);
    }
  }
  __syncthreads();

  // ================= Binv -> A = inv(Binv) =================
  if (tid < 16) {
    int s = tid >> 2, d = tid & 3;
    float2 acc = sW[s][d];
    acc = cadd(acc, cmul(sW[s][NS+0], sJ[0][d]));
    acc = cadd(acc, cmul(sW[s][NS+1], sJ[1][d]));
    sB[s][d] = acc;
    sB[s][NS+d] = (s==d) ? mkc(1.f,0.f) : mkc(0.f,0.f);
  }
  __syncthreads();
  if (tid == 0) {   // Gauss-Jordan with partial pivoting
    for (int col = 0; col < NS; ++col) {
      int piv = col; float best = cmag2(sB[col][col]);
      for (int r = col+1; r < NS; ++r) { float m = cmag2(sB[r][col]); if (m > best) { best = m; piv = r; } }
      if (piv != col) for (int k = 0; k < 2*NS; ++k) { float2 t = sB[col][k]; sB[col][k] = sB[piv][k]; sB[piv][k] = t; }
      float2 ip = cinv(sB[col][col]);
      for (int k = 0; k < 2*NS; ++k) sB[col][k] = cmul(sB[col][k], ip);
      for (int r = 0; r < NS; ++r) if (r != col) {
        float2 fac = sB[r][col];
        for (int k = 0; k < 2*NS; ++k) sB[r][k] = csub(sB[r][k], cmul(fac, sB[col][k]));
      }
    }
  }
  __syncthreads();
  if (tid < 16) sA[tid>>2][tid&3] = sB[tid>>2][NS + (tid&3)];
  __syncthreads();

  // ================= type3 loop (barrier-free; X immutable, H dead) =========
  {
    int c = wv;
    for (int src = 0; src < NC; ++src) {
      for (int tap = 0; tap < NT; ++tap) {
        const int shift = NDLY + tap;
        float nr = 0.f, ni = 0.f, dd = 0.f;
        for (int n = lane; n < NFR; n += 64) {
          float2 xs = (n >= shift) ? sX[src][n-shift] : mkc(0.f,0.f);
          float2 y = sY[c][n]; float wgt = sw[c][n];
          nr += wgt*(y.x*xs.x + y.y*xs.y);
          ni += wgt*(y.y*xs.x - y.x*xs.y);
          dd += wgt*(xs.x*xs.x + xs.y*xs.y);
        }
        nr = wred64(nr); ni = wred64(ni); dd = wred64(dd);  // no 1/N
        float2 vc = cscale(mkc(nr,ni), 1.0f/fmaxf(dd, EPSF));
        for (int n = lane; n < NFR; n += 64) {
          float2 xs = (n >= shift) ? sX[src][n-shift] : mkc(0.f,0.f);
          sY[c][n] = csub(sY[c][n], cmul(vc, xs));
        }
      }
    }
  }
  __syncthreads();

  // ---- store back: complex Y/Z/state to workspace, re(Y) to d_out
  for (int c = 0; c < NS; ++c) {
    const size_t yb = ((size_t)(b*NS+c)*NFQ + f)*NFR;
    for (int n = tid; n < NFR; n += 256) {
      float2 y = sY[c][n];
      Yg[yb+n] = y;
      outR[yb+n] = y.x;     // reference output = float32(real(Y))
    }
  }
  for (int k = 0; k < NBK; ++k) {
    const size_t zb = ((size_t)(b*NBK+k)*NFQ + f)*NFR;
    for (int n = tid; n < NFR; n += 256) Zg[zb+n] = sZ[k][n];
  }
  if (tid < NS*NC) Wg[((size_t)(b*NS + tid/NC)*NFQ + f)*NC + tid%NC] = sW[tid/NC][tid%NC];
  else if (tid < NS*NC + NBK*NS) { int t = tid - NS*NC; Jg[((size_t)(b*NBK + t/NS)*NFQ + f)*NS + t%NS] = sJ[t/NS][t%NS]; }
  else if (tid < NS*NC + NBK*NS + NS*NS) { int t = tid - NS*NC - NBK*NS; Ag[((size_t)(b*NS + t/NS)*NFQ + f)*NS + t%NS] = sA[t/NS][t%NS]; }
}

// ---------------------------------------------------------------------------
extern "C" void kernel_launch(void* const* d_in, const int* in_sizes, int n_in,
                              void* d_out, int out_size, void* d_ws, size_t ws_size,
                              hipStream_t stream)
{
  (void)in_sizes; (void)n_in; (void)out_size; (void)ws_size;
  const float* Xr = (const float*)d_in[0];
  const float* Xi = (const float*)d_in[1];
  float* outR = (float*)d_out;   // d_out = re(Y), float32, (2,4,320,500)

  char* ws = (char*)d_ws;
  size_t off = 0;
  float2* Yg = (float2*)(ws + off); off += (size_t)NB*NS*NFQ*NFR*sizeof(float2);  // 10,240,000
  float2* Zg = (float2*)(ws + off); off += (size_t)NB*NBK*NFQ*NFR*sizeof(float2); //  5,120,000
  float2* Wg = (float2*)(ws + off); off += (size_t)NB*NS*NFQ*NC*sizeof(float2);   //    122,880
  float2* Jg = (float2*)(ws + off); off += (size_t)NB*NBK*NFQ*NS*sizeof(float2);  //     40,960
  float2* Ag = (float2*)(ws + off); off += (size_t)NB*NS*NFQ*NS*sizeof(float2);   //     81,920
  float*  wg = (float*)(ws + off);  off += (size_t)NB*NS*NFR*sizeof(float);       //     16,000

  k_init<<<NB*NFQ, 256, 0, stream>>>(Xr, Xi, Yg, Zg, Wg, Jg, Ag);
  for (int it = 0; it < 2; ++it) {
    k_w<<<NB*NS, 512, 0, stream>>>(Yg, wg);
    k_iter<<<NB*NFQ, 256, 0, stream>>>(Xr, Xi, Yg, Zg, Wg, Jg, Ag, wg, outR);
  }
}

// Round 3
// 157.623 us; speedup vs baseline: 2.2001x; 2.2001x over previous
//
#include <hip/hip_runtime.h>

#define NFR 500   // n_frames
#define NFQ 320   // n_freq
#define NB  2     // batch
#define NC  6     // n_chan
#define NS  4     // n_src
#define NBK 2     // n_chan - n_src
#define NT  4     // n_taps
#define NDLY 1    // n_delay
#define EPSF 1e-3f
#define TINYF 1e-20f

#define NP   512            // padded frame count (8 x 64 lanes)
#define XPAD 8              // leading zero-pad for shifted X reads
#define XLEN (XPAD + NP)
#define NCH  8              // f-chunks for w partial sums
#define FPC  (NFQ / NCH)    // 40 freqs per chunk

__device__ __forceinline__ float2 mkc(float r, float i){ return make_float2(r,i); }
__device__ __forceinline__ float2 cadd(float2 a, float2 b){ return mkc(a.x+b.x, a.y+b.y); }
__device__ __forceinline__ float2 csub(float2 a, float2 b){ return mkc(a.x-b.x, a.y-b.y); }
__device__ __forceinline__ float2 cmul(float2 a, float2 b){ return mkc(a.x*b.x - a.y*b.y, a.x*b.y + a.y*b.x); }
__device__ __forceinline__ float2 cmulc(float2 a, float2 b){ // a * conj(b)
  return mkc(a.x*b.x + a.y*b.y, a.y*b.x - a.x*b.y);
}
__device__ __forceinline__ float2 conjc(float2 a){ return mkc(a.x, -a.y); }
__device__ __forceinline__ float  cmag2(float2 a){ return a.x*a.x + a.y*a.y; }
__device__ __forceinline__ float2 cscale(float2 a, float s){ return mkc(a.x*s, a.y*s); }
__device__ __forceinline__ float2 cinv(float2 a){ float m = a.x*a.x + a.y*a.y; return mkc(a.x/m, -a.y/m); }

__device__ __forceinline__ float wred64(float v){
#pragma unroll
  for (int o = 32; o > 0; o >>= 1) v += __shfl_xor(v, o, 64);
  return v;
}

// ---------------------------------------------------------------------------
// init: C_XX -> J (4x4 diag-loaded solve), W/A = eye, Y = X[:4], Z = J X - X[4:]
// ---------------------------------------------------------------------------
__global__ __launch_bounds__(256) void k_init(
  const float* __restrict__ Xr, const float* __restrict__ Xi,
  float2* __restrict__ Yg, float2* __restrict__ Zg,
  float2* __restrict__ Wg, float2* __restrict__ Jg, float2* __restrict__ Ag)
{
  __shared__ float2 sX[NC][NFR];
  __shared__ float2 sC[NS][NC];
  __shared__ float2 sJl[NBK][NS];

  const int bf = blockIdx.x;
  const int b = bf / NFQ, f = bf % NFQ;
  const int tid = threadIdx.x, wv = tid >> 6, lane = tid & 63;

  for (int c = 0; c < NC; ++c) {
    const size_t base = ((size_t)(b*NC + c)*NFQ + f)*NFR;
    for (int n = tid; n < NFR; n += 256)
      sX[c][n] = mkc(Xr[base+n], Xi[base+n]);
  }
  __syncthreads();

  for (int p = wv; p < NS*NC; p += 4) {
    int s = p / NC, d = p % NC;
    float ar = 0.f, ai = 0.f;
    for (int n = lane; n < NFR; n += 64) {
      float2 xs = sX[s][n], xd = sX[d][n];
      ar += xs.x*xd.x + xs.y*xd.y;
      ai += xs.y*xd.x - xs.x*xd.y;
    }
    ar = wred64(ar); ai = wred64(ai);
    if (lane == 0) sC[s][d] = mkc(ar*(1.f/NFR), ai*(1.f/NFR));
  }
  __syncthreads();

  if (tid == 0) {
    float2 M[NS][NC];
    for (int s = 0; s < NS; ++s)
      for (int d = 0; d < NC; ++d) M[s][d] = sC[s][d];
    float dsum = 0.f;
    for (int s = 0; s < NS; ++s) dsum += sqrtf(cmag2(M[s][s]));
    float load = fmaxf(dsum*1e-5f, 1e-5f);
    for (int s = 0; s < NS; ++s) M[s][s].x += load;
    for (int col = 0; col < NS; ++col) {
      int piv = col; float best = cmag2(M[col][col]);
      for (int r = col+1; r < NS; ++r) { float m = cmag2(M[r][col]); if (m > best){best=m; piv=r;} }
      if (piv != col) for (int k = 0; k < NC; ++k) { float2 t=M[col][k]; M[col][k]=M[piv][k]; M[piv][k]=t; }
      float2 ip = cinv(M[col][col]);
      for (int k = col; k < NC; ++k) M[col][k] = cmul(M[col][k], ip);
      for (int r = 0; r < NS; ++r) if (r != col) {
        float2 fac = M[r][col];
        for (int k = col; k < NC; ++k) M[r][k] = csub(M[r][k], cmul(fac, M[col][k]));
      }
    }
    for (int k = 0; k < NBK; ++k)
      for (int s = 0; s < NS; ++s) sJl[k][s] = conjc(M[s][NS+k]);
  }
  __syncthreads();

  if (tid < NBK*NS) {
    int k = tid / NS, s = tid % NS;
    Jg[((size_t)(b*NBK+k)*NFQ + f)*NS + s] = sJl[k][s];
  } else if (tid < NBK*NS + NS*NC) {
    int t = tid - NBK*NS; int s = t / NC, d = t % NC;
    Wg[((size_t)(b*NS+s)*NFQ + f)*NC + d] = (s==d) ? mkc(1.f,0.f) : mkc(0.f,0.f);
  } else if (tid < NBK*NS + NS*NC + NS*NS) {
    int t = tid - NBK*NS - NS*NC; int s = t / NS, d = t % NS;
    Ag[((size_t)(b*NS+s)*NFQ + f)*NS + d] = (s==d) ? mkc(1.f,0.f) : mkc(0.f,0.f);
  }
  for (int c = 0; c < NS; ++c) {
    const size_t base = ((size_t)(b*NS + c)*NFQ + f)*NFR;
    for (int n = tid; n < NFR; n += 256) Yg[base+n] = sX[c][n];
  }
  for (int k = 0; k < NBK; ++k) {
    const size_t base = ((size_t)(b*NBK + k)*NFQ + f)*NFR;
    for (int n = tid; n < NFR; n += 256) {
      float2 acc = cscale(sX[NS+k][n], -1.f);
      for (int s = 0; s < NS; ++s) acc = cadd(acc, cmul(sJl[k][s], sX[s][n]));
      Zg[base+n] = acc;
    }
  }
}

// ---------------------------------------------------------------------------
// w partial sums: wacc[ch][bs][n] = sum_{f in chunk ch} |Y[bs,f,n]|^2
// (deterministic two-stage; k_iter finalizes 1/max(mean,eps) in its prologue)
// ---------------------------------------------------------------------------
__global__ __launch_bounds__(512) void k_wpart(const float2* __restrict__ Yg,
                                               float* __restrict__ wacc)
{
  const int bs = blockIdx.x / NCH;
  const int ch = blockIdx.x % NCH;
  const int n  = threadIdx.x;
  if (n >= NFR) return;
  const float2* row = Yg + (size_t)bs*NFQ*NFR;
  float acc = 0.f;
  for (int ff = 0; ff < FPC; ++ff) {
    float2 y = row[(size_t)(ch*FPC + ff)*NFR + n];
    acc += y.x*y.x + y.y*y.y;
  }
  wacc[((size_t)(ch*NB*NS + bs))*NFR + n] = acc;
}

// ---------------------------------------------------------------------------
// one full iss_updates iteration per (b,f) block. Y,w in registers (wave-owned
// channel); X zero-padded in LDS for branchless shifted reads; H dead.
// ---------------------------------------------------------------------------
__global__ __launch_bounds__(256, 3) void k_iter(
  const float* __restrict__ Xr, const float* __restrict__ Xi,
  float2* __restrict__ Yg, float2* __restrict__ Zg,
  float2* __restrict__ Wg, float2* __restrict__ Jg, float2* __restrict__ Ag,
  const float* __restrict__ wacc, float* __restrict__ outR, const int last)
{
  __shared__ float2 sXp[NC][XLEN];   // front- and back-padded X
  __shared__ float2 sZ[NBK][NP];
  __shared__ float2 sS[NP];
  __shared__ float2 sW[NS][NC];
  __shared__ float2 sJ[NBK][NS];
  __shared__ float2 sA[NS][NS];
  __shared__ float2 sB[NS][2*NS];
  __shared__ float2 sv[NC], sg[NC], sgo[NS], sp[NC];
  __shared__ float  sd[NC];
  __shared__ float2 sv2[NS], sAv[NS], sgA[NS], sWsrc[NC];

  const int bf = blockIdx.x;
  const int b = bf / NFQ, f = bf % NFQ;
  const int tid = threadIdx.x, wv = tid >> 6, lane = tid & 63;

  float2 yreg[8];   // wave-owned channel wv: Y[n], n = lane + 64*i (0 beyond NFR)
  float  wreg[8];   // w[b, wv, n] (0 beyond NFR)

  // ---- stage X (zero-padded both ends)
  for (int c = 0; c < NC; ++c) {
    const size_t base = ((size_t)(b*NC + c)*NFQ + f)*NFR;
    for (int j = tid; j < XLEN; j += 256) {
      int n = j - XPAD;
      sXp[c][j] = (n >= 0 && n < NFR) ? mkc(Xr[base+n], Xi[base+n]) : mkc(0.f,0.f);
    }
  }
  // ---- stage Z (zero-padded tail)
  for (int k = 0; k < NBK; ++k) {
    const size_t zb = ((size_t)(b*NBK + k)*NFQ + f)*NFR;
    for (int n = tid; n < NP; n += 256) sZ[k][n] = (n < NFR) ? Zg[zb+n] : mkc(0.f,0.f);
  }
  // ---- Y + w into registers
  {
    const size_t yb = ((size_t)(b*NS + wv)*NFQ + f)*NFR;
    const int bs = b*NS + wv;
#pragma unroll
    for (int i = 0; i < 8; ++i) {
      int n = lane + 64*i;
      if (n < NFR) {
        yreg[i] = Yg[yb+n];
        float a = 0.f;
#pragma unroll
        for (int ch = 0; ch < NCH; ++ch) a += wacc[((size_t)(ch*NB*NS + bs))*NFR + n];
        wreg[i] = 1.0f / fmaxf(a * (1.0f/(float)NFQ), EPSF);
      } else { yreg[i] = mkc(0.f,0.f); wreg[i] = 0.f; }
    }
  }
  if (tid < NS*NC) sW[tid/NC][tid%NC] = Wg[((size_t)(b*NS + tid/NC)*NFQ + f)*NC + tid%NC];
  else if (tid < NS*NC + NBK*NS) { int t=tid-NS*NC; sJ[t/NS][t%NS] = Jg[((size_t)(b*NBK+t/NS)*NFQ+f)*NS + t%NS]; }
  else if (tid < NS*NC + NBK*NS + NS*NS) { int t=tid-NS*NC-NBK*NS; sA[t/NS][t%NS] = Ag[((size_t)(b*NS+t/NS)*NFQ+f)*NS + t%NS]; }
  __syncthreads();

  // ================= bak loop: bak_update + mat_up2 =================
  for (int bak = 0; bak < NBK; ++bak) {
    // --- phase S: Zs = Z[bak] + X[4+bak]
    for (int n = tid; n < NP; n += 256)
      sS[n] = cadd(sZ[bak][n], sXp[NS+bak][XPAD+n]);
    __syncthreads();

    // --- phase R: p,d reductions (+ g on wave-0 lanes)
    {
      // own channel c = wv (weighted)
      float pr = 0.f, pi = 0.f, dd = 0.f;
#pragma unroll
      for (int i = 0; i < 8; ++i) {
        float2 y = yreg[i]; float2 zs = sS[lane+64*i]; float wgt = wreg[i];
        pr += wgt*(y.x*zs.x + y.y*zs.y);
        pi += wgt*(y.y*zs.x - y.x*zs.y);
        dd += wgt*(zs.x*zs.x + zs.y*zs.y);
      }
      pr = wred64(pr); pi = wred64(pi); dd = wred64(dd);
      if (lane == 0) { sp[wv] = mkc(pr*(1.f/NFR), pi*(1.f/NFR)); sd[wv] = dd*(1.f/NFR); }
      // channels 4,5 on waves 0,1 (unweighted, Y:=Z rows)
      if (wv < NBK) {
        float qr = 0.f, qi = 0.f, qd = 0.f;
#pragma unroll
        for (int i = 0; i < 8; ++i) {
          float2 y = sZ[wv][lane+64*i]; float2 zs = sS[lane+64*i];
          qr += (y.x*zs.x + y.y*zs.y);
          qi += (y.y*zs.x - y.x*zs.y);
          qd += (zs.x*zs.x + zs.y*zs.y);
        }
        qr = wred64(qr); qi = wred64(qi); qd = wred64(qd);
        if (lane == 0) { sp[NS+wv] = mkc(qr*(1.f/NFR), qi*(1.f/NFR)); sd[NS+wv] = qd*(1.f/NFR); }
      }
    }
    // g[c] = conj( sum_s J[bak][s] * A2[s][c] )  (independent of p,d)
    if (tid < NC) {
      int c = tid; float2 acc = mkc(0.f,0.f);
      for (int s = 0; s < NS; ++s) {
        float2 a2;
        if (c < NS) a2 = sA[s][c];
        else {
          a2 = mkc(0.f,0.f);
          for (int k = 0; k < NS; ++k) a2 = cadd(a2, cmul(sA[s][k], sW[k][c]));
        }
        acc = cadd(acc, cmul(sJ[bak][s], a2));
      }
      sg[c] = conjc(acc);
    }
    __syncthreads();

    // --- phase V: scalars + v + capture g_old=J[bak] (single thread)
    if (tid == 0) {
      float gdg = 0.f; float2 gdp = mkc(0.f,0.f);
      for (int c = 0; c < NC; ++c) {
        float id = 1.0f/(sd[c] + EPSF);
        gdg += cmag2(sg[c]) * id;
        float2 t = cmulc(sp[c], sg[c]);
        gdp.x += t.x*id; gdp.y += t.y*id;
      }
      float2 bb = mkc(1.0f - gdp.x, -gdp.y);
      float b1 = cmag2(bb);
      float a = b1*gdg + TINYF;
      float beta = (-b1 + sqrtf(b1*b1 + 4.0f*a)) / (2.0f*a);
      float2 ell;
      if (b1 > EPSF*EPSF) ell = cscale(bb, beta);
      else { float e2 = 1.0f/sqrtf(EPSF + gdg); ell = mkc(e2, 0.f); }
      for (int c = 0; c < NC; ++c)
        sv[c] = cscale(csub(sp[c], cmul(ell, sg[c])), 1.0f/(sd[c] + EPSF));
      for (int s = 0; s < NS; ++s) sgo[s] = sJ[bak][s];
    }
    __syncthreads();

    // --- phase U: YZ -= v (x) Zs ; v2
    {
      float2 vc = sv[wv];
#pragma unroll
      for (int i = 0; i < 8; ++i) yreg[i] = csub(yreg[i], cmul(vc, sS[lane+64*i]));
      if (wv < NBK) {
        float2 v2c = sv[NS+wv];
#pragma unroll
        for (int i = 0; i < 8; ++i) {
          int n = lane+64*i;
          sZ[wv][n] = csub(sZ[wv][n], cmul(v2c, sS[n]));
        }
      }
    }
    if (tid < NS) {
      float2 t = sv[tid];
      t = cadd(t, cmul(sW[tid][NS+0], sv[NS+0]));
      t = cadd(t, cmul(sW[tid][NS+1], sv[NS+1]));
      sv2[tid] = t;
    }
    __syncthreads();

    // --- phase P1: Av, gA, W/J rank-1 updates (disjoint threads)
    if (tid < NS) {
      float2 acc = mkc(0.f,0.f);
      for (int c = 0; c < NS; ++c) acc = cadd(acc, cmul(sA[tid][c], sv2[c]));
      sAv[tid] = acc;
    } else if (tid < 2*NS) {
      int c = tid - NS; float2 acc = mkc(0.f,0.f);
      for (int s = 0; s < NS; ++s) acc = cadd(acc, cmul(sgo[s], sA[s][c]));
      sgA[c] = acc;
    } else if (tid < 2*NS + 16) {
      int idx = tid - 2*NS; int cc = idx >> 2, d = idx & 3;
      sW[cc][d] = csub(sW[cc][d], cmul(sv[cc], sgo[d]));
    } else if (tid < 2*NS + 16 + 8) {
      int idx = tid - 2*NS - 16; int k = idx >> 2, d = idx & 3;
      sJ[k][d] = csub(sJ[k][d], cmul(sv[NS+k], sgo[d]));
    }
    __syncthreads();

    // --- phase P2: A update (mul computed redundantly)
    if (tid < 16) {
      int s = tid >> 2, c = tid & 3;
      float2 den = mkc(1.f,0.f);
      for (int cc = 0; cc < NS; ++cc) den = csub(den, cmul(sv2[cc], sgA[cc]));
      float m2 = cmag2(den) + EPSF;
      float2 mul = mkc(den.x/m2, -den.y/m2);
      sA[s][c] = cadd(sA[s][c], cmul(sAv[s], cmul(sgA[c], mul)));
    }
    __syncthreads();
  }

  // ================= type1 loop (src) + mat_up1 =================
  for (int src = 0; src < NS; ++src) {
    // phase A: stage Ys, W[src] row copy; previous src's mat_up1
    if (wv == src) {
#pragma unroll
      for (int i = 0; i < 8; ++i) sS[lane+64*i] = yreg[i];
    }
    if (tid < NC) sWsrc[tid] = sW[src][tid];
    if (src > 0 && tid >= 8 && tid < 8+NS) {
      int r = tid - 8, prev = src - 1;
      float2 acc = mkc(0.f,0.f);
      for (int c = 0; c < NS; ++c) acc = cadd(acc, cmul(sA[r][c], sv[c]));
      float den = 1.0f - sv[prev].x + EPSF;
      sA[r][prev] = cadd(sA[r][prev], cscale(acc, 1.0f/den));
    }
    __syncthreads();

    // phase B: reduce + v + updates (wave-owned)
    {
      int c = wv;
      float nr = 0.f, ni = 0.f, dd = 0.f;
#pragma unroll
      for (int i = 0; i < 8; ++i) {
        float2 y = yreg[i]; float2 s = sS[lane+64*i]; float wgt = wreg[i];
        nr += wgt*(y.x*s.x + y.y*s.y);
        ni += wgt*(y.y*s.x - y.x*s.y);
        dd += wgt*(s.x*s.x + s.y*s.y);
      }
      nr = wred64(nr)*(1.f/NFR); ni = wred64(ni)*(1.f/NFR); dd = wred64(dd)*(1.f/NFR);
      float2 vc;
      if (c == src) vc = mkc(1.0f - 1.0f/sqrtf(fmaxf(dd, EPSF)), 0.f);
      else          vc = cscale(mkc(nr, ni), 1.0f/fmaxf(dd, EPSF));
      if (lane == 0) sv[c] = vc;
#pragma unroll
      for (int i = 0; i < 8; ++i) yreg[i] = csub(yreg[i], cmul(vc, sS[lane+64*i]));
      if (lane < NC) sW[c][lane] = csub(sW[c][lane], cmul(vc, sWsrc[lane]));
    }
    __syncthreads();
  }
  // (mat_up1 for src=3 is dead: A is overwritten by the Binv inverse below)

  // ================= type2 loop (barrier-free; wave owns Y[c], W row c) =====
  {
    int c = wv;
    for (int bak = 0; bak < NBK; ++bak) {
      float nr = 0.f, ni = 0.f, dd = 0.f;
#pragma unroll
      for (int i = 0; i < 8; ++i) {
        float2 y = yreg[i]; float2 z = sZ[bak][lane+64*i]; float wgt = wreg[i];
        nr += wgt*(y.x*z.x + y.y*z.y);
        ni += wgt*(y.y*z.x - y.x*z.y);
        dd += wgt*(z.x*z.x + z.y*z.y);
      }
      nr = wred64(nr); ni = wred64(ni); dd = wred64(dd);   // no 1/N
      float2 vc = cscale(mkc(nr,ni), 1.0f/fmaxf(dd, EPSF));
#pragma unroll
      for (int i = 0; i < 8; ++i) yreg[i] = csub(yreg[i], cmul(vc, sZ[bak][lane+64*i]));
      if (lane < NS) sW[c][lane] = csub(sW[c][lane], cmul(vc, sJ[bak][lane]));
      if (lane == NS) sW[c][NS+bak] = cadd(sW[c][NS+bak], vc);
    }
  }
  __syncthreads();

  // ================= Binv -> A = inv(Binv) =================
  if (tid < 16) {
    int s = tid >> 2, d = tid & 3;
    float2 acc = sW[s][d];
    acc = cadd(acc, cmul(sW[s][NS+0], sJ[0][d]));
    acc = cadd(acc, cmul(sW[s][NS+1], sJ[1][d]));
    sB[s][d] = acc;
    sB[s][NS+d] = (s==d) ? mkc(1.f,0.f) : mkc(0.f,0.f);
  }
  __syncthreads();
  if (tid == 0) {
    for (int col = 0; col < NS; ++col) {
      int piv = col; float best = cmag2(sB[col][col]);
      for (int r = col+1; r < NS; ++r) { float m = cmag2(sB[r][col]); if (m > best) { best = m; piv = r; } }
      if (piv != col) for (int k = 0; k < 2*NS; ++k) { float2 t = sB[col][k]; sB[col][k] = sB[piv][k]; sB[piv][k] = t; }
      float2 ip = cinv(sB[col][col]);
      for (int k = 0; k < 2*NS; ++k) sB[col][k] = cmul(sB[col][k], ip);
      for (int r = 0; r < NS; ++r) if (r != col) {
        float2 fac = sB[r][col];
        for (int k = 0; k < 2*NS; ++k) sB[r][k] = csub(sB[r][k], cmul(fac, sB[col][k]));
      }
    }
  }
  __syncthreads();

  // ================= type3 loop (barrier-free; padded X, regs Y/w) =========
  {
    for (int src = 0; src < NC; ++src) {
      const float2* __restrict__ xrow = &sXp[src][0];
#pragma unroll
      for (int tap = 0; tap < NT; ++tap) {
        const int xoff = XPAD - (NDLY + tap) + lane;
        float nr = 0.f, ni = 0.f, dd = 0.f;
#pragma unroll
        for (int i = 0; i < 8; ++i) {
          float2 xs = xrow[xoff + 64*i];
          float2 y = yreg[i]; float wgt = wreg[i];
          nr += wgt*(y.x*xs.x + y.y*xs.y);
          ni += wgt*(y.y*xs.x - y.x*xs.y);
          dd += wgt*(xs.x*xs.x + xs.y*xs.y);
        }
        nr = wred64(nr); ni = wred64(ni); dd = wred64(dd);  // no 1/N
        float2 vc = cscale(mkc(nr,ni), 1.0f/fmaxf(dd, EPSF));
#pragma unroll
        for (int i = 0; i < 8; ++i) {
          float2 xs = xrow[xoff + 64*i];
          yreg[i] = csub(yreg[i], cmul(vc, xs));
        }
      }
    }
  }

  // ================= epilogue =================
  {
    const size_t yb = ((size_t)(b*NS + wv)*NFQ + f)*NFR;
    if (last) {
#pragma unroll
      for (int i = 0; i < 8; ++i) { int n = lane+64*i; if (n < NFR) outR[yb+n] = yreg[i].x; }
    } else {
#pragma unroll
      for (int i = 0; i < 8; ++i) { int n = lane+64*i; if (n < NFR) Yg[yb+n] = yreg[i]; }
    }
  }
  if (!last) {
    for (int k = 0; k < NBK; ++k) {
      const size_t zb = ((size_t)(b*NBK+k)*NFQ + f)*NFR;
      for (int n = tid; n < NFR; n += 256) Zg[zb+n] = sZ[k][n];
    }
    if (tid < NS*NC) Wg[((size_t)(b*NS + tid/NC)*NFQ + f)*NC + tid%NC] = sW[tid/NC][tid%NC];
    else if (tid < NS*NC + NBK*NS) { int t = tid - NS*NC; Jg[((size_t)(b*NBK + t/NS)*NFQ + f)*NS + t%NS] = sJ[t/NS][t%NS]; }
    else if (tid < NS*NC + NBK*NS + NS*NS) { int t = tid - NS*NC - NBK*NS; Ag[((size_t)(b*NS + t/NS)*NFQ + f)*NS + t%NS] = sB[t/NS][NS + t%NS]; }
  }
}

// ---------------------------------------------------------------------------
extern "C" void kernel_launch(void* const* d_in, const int* in_sizes, int n_in,
                              void* d_out, int out_size, void* d_ws, size_t ws_size,
                              hipStream_t stream)
{
  (void)in_sizes; (void)n_in; (void)out_size; (void)ws_size;
  const float* Xr = (const float*)d_in[0];
  const float* Xi = (const float*)d_in[1];
  float* outR = (float*)d_out;   // d_out = re(Y), float32, (2,4,320,500)

  char* ws = (char*)d_ws;
  size_t off = 0;
  float2* Yg = (float2*)(ws + off); off += (size_t)NB*NS*NFQ*NFR*sizeof(float2);  // 10,240,000
  float2* Zg = (float2*)(ws + off); off += (size_t)NB*NBK*NFQ*NFR*sizeof(float2); //  5,120,000
  float2* Wg = (float2*)(ws + off); off += (size_t)NB*NS*NFQ*NC*sizeof(float2);   //    122,880
  float2* Jg = (float2*)(ws + off); off += (size_t)NB*NBK*NFQ*NS*sizeof(float2);  //     40,960
  float2* Ag = (float2*)(ws + off); off += (size_t)NB*NS*NFQ*NS*sizeof(float2);   //     81,920
  float*  wacc = (float*)(ws + off); off += (size_t)NCH*NB*NS*NFR*sizeof(float);  //    128,000

  k_init<<<NB*NFQ, 256, 0, stream>>>(Xr, Xi, Yg, Zg, Wg, Jg, Ag);
  for (int it = 0; it < 2; ++it) {
    k_wpart<<<NB*NS*NCH, 512, 0, stream>>>(Yg, wacc);
    k_iter<<<NB*NFQ, 256, 0, stream>>>(Xr, Xi, Yg, Zg, Wg, Jg, Ag, wacc, outR, it == 1);
  }
}

// Round 4
// 145.958 us; speedup vs baseline: 2.3759x; 1.0799x over previous
//
#include <hip/hip_runtime.h>

#define NFR 500   // n_frames
#define NFQ 320   // n_freq
#define NB  2     // batch
#define NC  6     // n_chan
#define NS  4     // n_src
#define NBK 2     // n_chan - n_src
#define NT  4     // n_taps
#define NDLY 1    // n_delay
#define EPSF 1e-3f
#define TINYF 1e-20f

#define NP   512            // padded frame count (8 x 64 lanes)
#define XPAD 8              // leading zero-pad for shifted X reads
#define XLEN (XPAD + NP)
#define NCH  8              // f-chunks for w partial sums
#define FPC  (NFQ / NCH)    // 40 freqs per chunk

typedef float f2 __attribute__((ext_vector_type(2)));

__device__ __forceinline__ f2 mk2(float r, float i){ f2 t; t.x = r; t.y = i; return t; }
// complex ops on (re,im) pairs — written to select v_pk_* packed fp32
__device__ __forceinline__ f2 cmul(f2 a, f2 b){ return a.xx*b + a.yy*mk2(-b.y, b.x); }
__device__ __forceinline__ f2 cmulc(f2 a, f2 b){ return b.xx*a + b.yy*mk2(a.y, -a.x); } // a*conj(b)
__device__ __forceinline__ f2 conjc(f2 a){ return mk2(a.x, -a.y); }
__device__ __forceinline__ float cmag2(f2 a){ return a.x*a.x + a.y*a.y; }
__device__ __forceinline__ f2 cinv(f2 a){ float m = a.x*a.x + a.y*a.y; return mk2(a.x/m, -a.y/m); }

__device__ __forceinline__ float wred64(float v){
#pragma unroll
  for (int o = 32; o > 0; o >>= 1) v += __shfl_xor(v, o, 64);
  return v;
}

// ---------------------------------------------------------------------------
// init: C_XX -> J (4x4 diag-loaded solve), W/A = eye, Y = X[:4], Z = J X - X[4:]
// ---------------------------------------------------------------------------
__global__ __launch_bounds__(256) void k_init(
  const float* __restrict__ Xr, const float* __restrict__ Xi,
  f2* __restrict__ Yg, f2* __restrict__ Zg,
  f2* __restrict__ Wg, f2* __restrict__ Jg, f2* __restrict__ Ag)
{
  __shared__ f2 sX[NC][NFR];
  __shared__ f2 sC[NS][NC];
  __shared__ f2 sJl[NBK][NS];

  const int bf = blockIdx.x;
  const int b = bf / NFQ, f = bf % NFQ;
  const int tid = threadIdx.x, wv = tid >> 6, lane = tid & 63;

  for (int c = 0; c < NC; ++c) {
    const size_t base = ((size_t)(b*NC + c)*NFQ + f)*NFR;
    for (int n = tid; n < NFR; n += 256)
      sX[c][n] = mk2(Xr[base+n], Xi[base+n]);
  }
  __syncthreads();

  // C_XX[s][d] = (1/N) sum_n X_s conj(X_d), s<4, d<6
  for (int p = wv; p < NS*NC; p += 4) {
    int s = p / NC, d = p % NC;
    f2 ar2 = mk2(0.f,0.f), ai2 = mk2(0.f,0.f);
    for (int n = lane; n < NFR; n += 64) {
      f2 xs = sX[s][n], xd = sX[d][n];
      ar2 += xs * xd;                       // re: xs.x xd.x + xs.y xd.y
      ai2 += xs.yx * mk2(xd.x, -xd.y);      // im: xs.y xd.x - xs.x xd.y
    }
    float ar = wred64(ar2.x + ar2.y), ai = wred64(ai2.x + ai2.y);
    if (lane == 0) sC[s][d] = mk2(ar*(1.f/NFR), ai*(1.f/NFR));
  }
  __syncthreads();

  if (tid == 0) {
    f2 M[NS][NC];
    for (int s = 0; s < NS; ++s)
      for (int d = 0; d < NC; ++d) M[s][d] = sC[s][d];
    float dsum = 0.f;
    for (int s = 0; s < NS; ++s) dsum += sqrtf(cmag2(M[s][s]));
    float load = fmaxf(dsum*1e-5f, 1e-5f);
    for (int s = 0; s < NS; ++s) M[s][s].x += load;
    for (int col = 0; col < NS; ++col) {
      int piv = col; float best = cmag2(M[col][col]);
      for (int r = col+1; r < NS; ++r) { float m = cmag2(M[r][col]); if (m > best){best=m; piv=r;} }
      if (piv != col) for (int k = 0; k < NC; ++k) { f2 t=M[col][k]; M[col][k]=M[piv][k]; M[piv][k]=t; }
      f2 ip = cinv(M[col][col]);
      for (int k = col; k < NC; ++k) M[col][k] = cmul(M[col][k], ip);
      for (int r = 0; r < NS; ++r) if (r != col) {
        f2 fac = M[r][col];
        for (int k = col; k < NC; ++k) M[r][k] -= cmul(fac, M[col][k]);
      }
    }
    for (int k = 0; k < NBK; ++k)
      for (int s = 0; s < NS; ++s) sJl[k][s] = conjc(M[s][NS+k]);
  }
  __syncthreads();

  if (tid < NBK*NS) {
    int k = tid / NS, s = tid % NS;
    Jg[((size_t)(b*NBK+k)*NFQ + f)*NS + s] = sJl[k][s];
  } else if (tid < NBK*NS + NS*NC) {
    int t = tid - NBK*NS; int s = t / NC, d = t % NC;
    Wg[((size_t)(b*NS+s)*NFQ + f)*NC + d] = (s==d) ? mk2(1.f,0.f) : mk2(0.f,0.f);
  } else if (tid < NBK*NS + NS*NC + NS*NS) {
    int t = tid - NBK*NS - NS*NC; int s = t / NS, d = t % NS;
    Ag[((size_t)(b*NS+s)*NFQ + f)*NS + d] = (s==d) ? mk2(1.f,0.f) : mk2(0.f,0.f);
  }
  for (int c = 0; c < NS; ++c) {
    const size_t base = ((size_t)(b*NS + c)*NFQ + f)*NFR;
    for (int n = tid; n < NFR; n += 256) Yg[base+n] = sX[c][n];
  }
  for (int k = 0; k < NBK; ++k) {
    const size_t base = ((size_t)(b*NBK + k)*NFQ + f)*NFR;
    for (int n = tid; n < NFR; n += 256) {
      f2 acc = -sX[NS+k][n];
      for (int s = 0; s < NS; ++s) acc += cmul(sJl[k][s], sX[s][n]);
      Zg[base+n] = acc;
    }
  }
}

// ---------------------------------------------------------------------------
// w partial sums: wacc[ch][bs][n] = sum_{f in chunk ch} |Y[bs,f,n]|^2
// ---------------------------------------------------------------------------
__global__ __launch_bounds__(512) void k_wpart(const f2* __restrict__ Yg,
                                               float* __restrict__ wacc)
{
  const int bs = blockIdx.x / NCH;
  const int ch = blockIdx.x % NCH;
  const int n  = threadIdx.x;
  if (n >= NFR) return;
  const f2* row = Yg + (size_t)bs*NFQ*NFR;
  f2 acc2 = mk2(0.f,0.f);
  for (int ff = 0; ff < FPC; ++ff) {
    f2 y = row[(size_t)(ch*FPC + ff)*NFR + n];
    acc2 += y*y;
  }
  wacc[((size_t)(ch*NB*NS + bs))*NFR + n] = acc2.x + acc2.y;
}

// ---------------------------------------------------------------------------
// one full iss_updates iteration per (b,f) block. Y,w in registers (wave-owned
// channel); X zero-padded in LDS; packed-fp32 complex math; H dead.
// ---------------------------------------------------------------------------
__global__ __launch_bounds__(256, 4) void k_iter(
  const float* __restrict__ Xr, const float* __restrict__ Xi,
  f2* __restrict__ Yg, f2* __restrict__ Zg,
  f2* __restrict__ Wg, f2* __restrict__ Jg, f2* __restrict__ Ag,
  const float* __restrict__ wacc, float* __restrict__ outR, const int last)
{
  __shared__ f2 sXp[NC][XLEN];   // front/back zero-padded X
  __shared__ f2 sZ[NBK][NP];
  __shared__ f2 sS[NP];
  __shared__ f2 sW[NS][NC];
  __shared__ f2 sJ[NBK][NS];
  __shared__ f2 sA[NS][NS];
  __shared__ f2 sB[NS][2*NS];
  __shared__ f2 sv[NC], sg[NC], sgo[NS], sp[NC];
  __shared__ float sd[NC];
  __shared__ f2 sv2[NS], sAv[NS], sgA[NS], sWsrc[NC];

  const int bf = blockIdx.x;
  const int b = bf / NFQ, f = bf % NFQ;
  const int tid = threadIdx.x, wv = tid >> 6, lane = tid & 63;

  f2 yreg[8];   // wave-owned channel wv
  float wreg[8];

  // ---- stage X (zero-padded both ends)
  for (int c = 0; c < NC; ++c) {
    const size_t base = ((size_t)(b*NC + c)*NFQ + f)*NFR;
    for (int j = tid; j < XLEN; j += 256) {
      int n = j - XPAD;
      sXp[c][j] = (n >= 0 && n < NFR) ? mk2(Xr[base+n], Xi[base+n]) : mk2(0.f,0.f);
    }
  }
  // ---- stage Z (zero-padded tail)
  for (int k = 0; k < NBK; ++k) {
    const size_t zb = ((size_t)(b*NBK + k)*NFQ + f)*NFR;
    for (int n = tid; n < NP; n += 256) sZ[k][n] = (n < NFR) ? Zg[zb+n] : mk2(0.f,0.f);
  }
  // ---- Y + w into registers
  {
    const size_t yb = ((size_t)(b*NS + wv)*NFQ + f)*NFR;
    const int bs = b*NS + wv;
#pragma unroll
    for (int i = 0; i < 8; ++i) {
      int n = lane + 64*i;
      if (n < NFR) {
        yreg[i] = Yg[yb+n];
        float a = 0.f;
#pragma unroll
        for (int ch = 0; ch < NCH; ++ch) a += wacc[((size_t)(ch*NB*NS + bs))*NFR + n];
        wreg[i] = 1.0f / fmaxf(a * (1.0f/(float)NFQ), EPSF);
      } else { yreg[i] = mk2(0.f,0.f); wreg[i] = 0.f; }
    }
  }
  if (tid < NS*NC) sW[tid/NC][tid%NC] = Wg[((size_t)(b*NS + tid/NC)*NFQ + f)*NC + tid%NC];
  else if (tid < NS*NC + NBK*NS) { int t=tid-NS*NC; sJ[t/NS][t%NS] = Jg[((size_t)(b*NBK+t/NS)*NFQ+f)*NS + t%NS]; }
  else if (tid < NS*NC + NBK*NS + NS*NS) { int t=tid-NS*NC-NBK*NS; sA[t/NS][t%NS] = Ag[((size_t)(b*NS+t/NS)*NFQ+f)*NS + t%NS]; }
  __syncthreads();

  // ================= bak loop: bak_update + mat_up2 =================
  for (int bak = 0; bak < NBK; ++bak) {
    // --- phase S: Zs = Z[bak] + X[4+bak]
    for (int n = tid; n < NP; n += 256)
      sS[n] = sZ[bak][n] + sXp[NS+bak][XPAD+n];
    __syncthreads();

    f2 zs[8];   // cached Zs, reused across phases R and U
    // --- phase R: p,d reductions (+ g)
    {
      f2 pr2 = mk2(0.f,0.f), pi2 = mk2(0.f,0.f), dd2 = mk2(0.f,0.f);
#pragma unroll
      for (int i = 0; i < 8; ++i) {
        zs[i] = sS[lane+64*i];
        f2 wy = wreg[i]*yreg[i];
        pr2 += wy * zs[i];
        pi2 += wy.yx * mk2(zs[i].x, -zs[i].y);
        dd2 += (wreg[i]*zs[i]) * zs[i];
      }
      float pr = wred64(pr2.x+pr2.y), pi = wred64(pi2.x+pi2.y), dd = wred64(dd2.x+dd2.y);
      if (lane == 0) { sp[wv] = mk2(pr*(1.f/NFR), pi*(1.f/NFR)); sd[wv] = dd*(1.f/NFR); }
      if (wv < NBK) {   // channels 4,5 (unweighted, rows = Z)
        f2 qr2 = mk2(0.f,0.f), qi2 = mk2(0.f,0.f), qd2 = mk2(0.f,0.f);
#pragma unroll
        for (int i = 0; i < 8; ++i) {
          f2 y = sZ[wv][lane+64*i];
          qr2 += y * zs[i];
          qi2 += y.yx * mk2(zs[i].x, -zs[i].y);
          qd2 += zs[i]*zs[i];
        }
        float qr = wred64(qr2.x+qr2.y), qi = wred64(qi2.x+qi2.y), qd = wred64(qd2.x+qd2.y);
        if (lane == 0) { sp[NS+wv] = mk2(qr*(1.f/NFR), qi*(1.f/NFR)); sd[NS+wv] = qd*(1.f/NFR); }
      }
    }
    if (tid < NC) {   // g[c] = conj( sum_s J[bak][s] * A2[s][c] )
      int c = tid; f2 acc = mk2(0.f,0.f);
      for (int s = 0; s < NS; ++s) {
        f2 a2;
        if (c < NS) a2 = sA[s][c];
        else {
          a2 = mk2(0.f,0.f);
          for (int k = 0; k < NS; ++k) a2 += cmul(sA[s][k], sW[k][c]);
        }
        acc += cmul(sJ[bak][s], a2);
      }
      sg[c] = conjc(acc);
    }
    __syncthreads();

    // --- phase V: scalars + v + capture g_old = J[bak]
    if (tid == 0) {
      float gdg = 0.f; f2 gdp = mk2(0.f,0.f);
      for (int c = 0; c < NC; ++c) {
        float id = 1.0f/(sd[c] + EPSF);
        gdg += cmag2(sg[c]) * id;
        gdp += id * cmulc(sp[c], sg[c]);
      }
      f2 bb = mk2(1.0f - gdp.x, -gdp.y);
      float b1 = cmag2(bb);
      float a = b1*gdg + TINYF;
      float beta = (-b1 + sqrtf(b1*b1 + 4.0f*a)) / (2.0f*a);
      f2 ell;
      if (b1 > EPSF*EPSF) ell = beta * bb;
      else { float e2 = 1.0f/sqrtf(EPSF + gdg); ell = mk2(e2, 0.f); }
      for (int c = 0; c < NC; ++c)
        sv[c] = (1.0f/(sd[c] + EPSF)) * (sp[c] - cmul(ell, sg[c]));
      for (int s = 0; s < NS; ++s) sgo[s] = sJ[bak][s];
    }
    __syncthreads();

    // --- phase U: YZ -= v (x) Zs ; v2
    {
      f2 vc = sv[wv];
#pragma unroll
      for (int i = 0; i < 8; ++i) yreg[i] -= cmul(vc, zs[i]);
      if (wv < NBK) {
        f2 v2c = sv[NS+wv];
#pragma unroll
        for (int i = 0; i < 8; ++i) {
          int n = lane+64*i;
          sZ[wv][n] -= cmul(v2c, zs[i]);
        }
      }
    }
    if (tid < NS) {
      f2 t = sv[tid];
      t += cmul(sW[tid][NS+0], sv[NS+0]);
      t += cmul(sW[tid][NS+1], sv[NS+1]);
      sv2[tid] = t;
    }
    __syncthreads();

    // --- phase P1: Av, gA, W/J rank-1 updates (disjoint threads)
    if (tid < NS) {
      f2 acc = mk2(0.f,0.f);
      for (int c = 0; c < NS; ++c) acc += cmul(sA[tid][c], sv2[c]);
      sAv[tid] = acc;
    } else if (tid < 2*NS) {
      int c = tid - NS; f2 acc = mk2(0.f,0.f);
      for (int s = 0; s < NS; ++s) acc += cmul(sgo[s], sA[s][c]);
      sgA[c] = acc;
    } else if (tid < 2*NS + 16) {
      int idx = tid - 2*NS; int cc = idx >> 2, d = idx & 3;
      sW[cc][d] -= cmul(sv[cc], sgo[d]);
    } else if (tid < 2*NS + 16 + 8) {
      int idx = tid - 2*NS - 16; int k = idx >> 2, d = idx & 3;
      sJ[k][d] -= cmul(sv[NS+k], sgo[d]);
    }
    __syncthreads();

    // --- phase P2: A update (mul computed redundantly per thread)
    if (tid < 16) {
      int s = tid >> 2, c = tid & 3;
      f2 den = mk2(1.f,0.f);
      for (int cc = 0; cc < NS; ++cc) den -= cmul(sv2[cc], sgA[cc]);
      float m2 = cmag2(den) + EPSF;
      f2 mul = mk2(den.x/m2, -den.y/m2);
      sA[s][c] += cmul(sAv[s], cmul(sgA[c], mul));
    }
    __syncthreads();
  }

  // ================= type1 loop (src) + deferred mat_up1 =================
  for (int src = 0; src < NS; ++src) {
    if (wv == src) {
#pragma unroll
      for (int i = 0; i < 8; ++i) sS[lane+64*i] = yreg[i];
    }
    if (tid < NC) sWsrc[tid] = sW[src][tid];
    if (src > 0 && tid >= 8 && tid < 8+NS) {   // mat_up1 for previous src
      int r = tid - 8, prev = src - 1;
      f2 acc = mk2(0.f,0.f);
      for (int c = 0; c < NS; ++c) acc += cmul(sA[r][c], sv[c]);
      float den = 1.0f - sv[prev].x + EPSF;
      sA[r][prev] += (1.0f/den) * acc;
    }
    __syncthreads();

    {
      f2 ys[8];
      f2 nr2 = mk2(0.f,0.f), ni2 = mk2(0.f,0.f), dd2 = mk2(0.f,0.f);
#pragma unroll
      for (int i = 0; i < 8; ++i) {
        ys[i] = sS[lane+64*i];
        f2 wy = wreg[i]*yreg[i];
        nr2 += wy * ys[i];
        ni2 += wy.yx * mk2(ys[i].x, -ys[i].y);
        dd2 += (wreg[i]*ys[i]) * ys[i];
      }
      float nr = wred64(nr2.x+nr2.y)*(1.f/NFR);
      float ni = wred64(ni2.x+ni2.y)*(1.f/NFR);
      float dd = wred64(dd2.x+dd2.y)*(1.f/NFR);
      f2 vc;
      if (wv == src) vc = mk2(1.0f - 1.0f/sqrtf(fmaxf(dd, EPSF)), 0.f);
      else           vc = (1.0f/fmaxf(dd, EPSF)) * mk2(nr, ni);
      if (lane == 0) sv[wv] = vc;
#pragma unroll
      for (int i = 0; i < 8; ++i) yreg[i] -= cmul(vc, ys[i]);
      if (lane < NC) sW[wv][lane] -= cmul(vc, sWsrc[lane]);
    }
    __syncthreads();
  }
  // (mat_up1 for src=3 is dead: A is overwritten by the Binv inverse below)

  // ================= type2 loop (barrier-free; wave owns Y[c], W row c) =====
  {
    for (int bak = 0; bak < NBK; ++bak) {
      f2 zz[8];
      f2 nr2 = mk2(0.f,0.f), ni2 = mk2(0.f,0.f), dd2 = mk2(0.f,0.f);
#pragma unroll
      for (int i = 0; i < 8; ++i) {
        zz[i] = sZ[bak][lane+64*i];
        f2 wy = wreg[i]*yreg[i];
        nr2 += wy * zz[i];
        ni2 += wy.yx * mk2(zz[i].x, -zz[i].y);
        dd2 += (wreg[i]*zz[i]) * zz[i];
      }
      float nr = wred64(nr2.x+nr2.y), ni = wred64(ni2.x+ni2.y), dd = wred64(dd2.x+dd2.y);
      f2 vc = (1.0f/fmaxf(dd, EPSF)) * mk2(nr, ni);
#pragma unroll
      for (int i = 0; i < 8; ++i) yreg[i] -= cmul(vc, zz[i]);
      if (lane < NS) sW[wv][lane] -= cmul(vc, sJ[bak][lane]);
      if (lane == NS) sW[wv][NS+bak] += vc;
    }
  }
  __syncthreads();

  // ================= Binv -> A = inv(Binv) =================
  if (tid < 16) {
    int s = tid >> 2, d = tid & 3;
    f2 acc = sW[s][d];
    acc += cmul(sW[s][NS+0], sJ[0][d]);
    acc += cmul(sW[s][NS+1], sJ[1][d]);
    sB[s][d] = acc;
    sB[s][NS+d] = (s==d) ? mk2(1.f,0.f) : mk2(0.f,0.f);
  }
  __syncthreads();
  if (tid == 0) {
    for (int col = 0; col < NS; ++col) {
      int piv = col; float best = cmag2(sB[col][col]);
      for (int r = col+1; r < NS; ++r) { float m = cmag2(sB[r][col]); if (m > best) { best = m; piv = r; } }
      if (piv != col) for (int k = 0; k < 2*NS; ++k) { f2 t = sB[col][k]; sB[col][k] = sB[piv][k]; sB[piv][k] = t; }
      f2 ip = cinv(sB[col][col]);
      for (int k = 0; k < 2*NS; ++k) sB[col][k] = cmul(sB[col][k], ip);
      for (int r = 0; r < NS; ++r) if (r != col) {
        f2 fac = sB[r][col];
        for (int k = 0; k < 2*NS; ++k) sB[r][k] -= cmul(fac, sB[col][k]);
      }
    }
  }
  __syncthreads();

  // ================= type3 loop (barrier-free; padded X, regs Y/w) =========
  {
    for (int src = 0; src < NC; ++src) {
      const f2* __restrict__ xrow = &sXp[src][0];
#pragma unroll
      for (int tap = 0; tap < NT; ++tap) {
        const int xoff = XPAD - (NDLY + tap) + lane;
        f2 xs[8];
        f2 nr2 = mk2(0.f,0.f), ni2 = mk2(0.f,0.f), dd2 = mk2(0.f,0.f);
#pragma unroll
        for (int i = 0; i < 8; ++i) {
          xs[i] = xrow[xoff + 64*i];
          f2 wy = wreg[i]*yreg[i];
          nr2 += wy * xs[i];
          ni2 += wy.yx * mk2(xs[i].x, -xs[i].y);
          dd2 += (wreg[i]*xs[i]) * xs[i];
        }
        float nr = wred64(nr2.x+nr2.y), ni = wred64(ni2.x+ni2.y), dd = wred64(dd2.x+dd2.y);
        f2 vc = (1.0f/fmaxf(dd, EPSF)) * mk2(nr, ni);
#pragma unroll
        for (int i = 0; i < 8; ++i) yreg[i] -= cmul(vc, xs[i]);
      }
    }
  }

  // ================= epilogue =================
  {
    const size_t yb = ((size_t)(b*NS + wv)*NFQ + f)*NFR;
    if (last) {
#pragma unroll
      for (int i = 0; i < 8; ++i) { int n = lane+64*i; if (n < NFR) outR[yb+n] = yreg[i].x; }
    } else {
#pragma unroll
      for (int i = 0; i < 8; ++i) { int n = lane+64*i; if (n < NFR) Yg[yb+n] = yreg[i]; }
    }
  }
  if (!last) {
    for (int k = 0; k < NBK; ++k) {
      const size_t zb = ((size_t)(b*NBK+k)*NFQ + f)*NFR;
      for (int n = tid; n < NFR; n += 256) Zg[zb+n] = sZ[k][n];
    }
    if (tid < NS*NC) Wg[((size_t)(b*NS + tid/NC)*NFQ + f)*NC + tid%NC] = sW[tid/NC][tid%NC];
    else if (tid < NS*NC + NBK*NS) { int t = tid - NS*NC; Jg[((size_t)(b*NBK + t/NS)*NFQ + f)*NS + t%NS] = sJ[t/NS][t%NS]; }
    else if (tid < NS*NC + NBK*NS + NS*NS) { int t = tid - NS*NC - NBK*NS; Ag[((size_t)(b*NS + t/NS)*NFQ + f)*NS + t%NS] = sB[t/NS][NS + t%NS]; }
  }
}

// ---------------------------------------------------------------------------
extern "C" void kernel_launch(void* const* d_in, const int* in_sizes, int n_in,
                              void* d_out, int out_size, void* d_ws, size_t ws_size,
                              hipStream_t stream)
{
  (void)in_sizes; (void)n_in; (void)out_size; (void)ws_size;
  const float* Xr = (const float*)d_in[0];
  const float* Xi = (const float*)d_in[1];
  float* outR = (float*)d_out;   // d_out = re(Y), float32, (2,4,320,500)

  char* ws = (char*)d_ws;
  size_t off = 0;
  f2* Yg = (f2*)(ws + off); off += (size_t)NB*NS*NFQ*NFR*sizeof(f2);   // 10,240,000
  f2* Zg = (f2*)(ws + off); off += (size_t)NB*NBK*NFQ*NFR*sizeof(f2);  //  5,120,000
  f2* Wg = (f2*)(ws + off); off += (size_t)NB*NS*NFQ*NC*sizeof(f2);    //    122,880
  f2* Jg = (f2*)(ws + off); off += (size_t)NB*NBK*NFQ*NS*sizeof(f2);   //     40,960
  f2* Ag = (f2*)(ws + off); off += (size_t)NB*NS*NFQ*NS*sizeof(f2);    //     81,920
  float* wacc = (float*)(ws + off); off += (size_t)NCH*NB*NS*NFR*sizeof(float); // 128,000

  k_init<<<NB*NFQ, 256, 0, stream>>>(Xr, Xi, Yg, Zg, Wg, Jg, Ag);
  for (int it = 0; it < 2; ++it) {
    k_wpart<<<NB*NS*NCH, 512, 0, stream>>>(Yg, wacc);
    k_iter<<<NB*NFQ, 256, 0, stream>>>(Xr, Xi, Yg, Zg, Wg, Jg, Ag, wacc, outR, it == 1);
  }
}